// Round 11
// baseline (131.218 us; speedup 1.0000x reference)
//
#include <hip/hip_runtime.h>
#include <hip/hip_bf16.h>

#define NN 256
#define HH 256

typedef __attribute__((ext_vector_type(8))) short short8;
typedef __attribute__((ext_vector_type(4))) float f32x4;

__device__ __forceinline__ ushort f2bf(float x) {
    __hip_bfloat16 h = __float2bfloat16(x);
    return *reinterpret_cast<ushort*>(&h);
}
__device__ __forceinline__ float bf2f(ushort u) {
    __hip_bfloat16 h = *reinterpret_cast<__hip_bfloat16*>(&u);
    return __bfloat162float(h);
}
template <int CTRL>
__device__ __forceinline__ float dpp_add(float x) {
    int y = __builtin_amdgcn_update_dpp(0, __float_as_int(x), CTRL, 0xF, 0xF, true);
    return x + __int_as_float(y);
}
template <int CTRL>
__device__ __forceinline__ float dpp_max(float x) {
    int y = __builtin_amdgcn_update_dpp(0, __float_as_int(x), CTRL, 0xF, 0xF, true);
    return fmaxf(x, __int_as_float(y));
}
__device__ __forceinline__ float red16(float v) {
    v = dpp_add<0xB1>(v); v = dpp_add<0x4E>(v);
    v = dpp_add<0x141>(v); v = dpp_add<0x140>(v);
    return v;
}
__device__ __forceinline__ float red16max(float v) {
    v = dpp_max<0xB1>(v); v = dpp_max<0x4E>(v);
    v = dpp_max<0x141>(v); v = dpp_max<0x140>(v);
    return v;
}

// ws (float offsets), total 546,816 floats = 2,187,264 B
#define WS_Q   0        // Q[256][64]
#define WS_WA  16384    // WA[4][256]
#define WS_WB  17408    // WB[4][256]
#define WS_PV  18432    // PV[2][4][256][256]
#define WS_ML  542720   // ML[2][4][256][2]

// grid 80: [0,16) WA/WB | [16,80) Q rows
__global__ __launch_bounds__(256) void precompute_kernel(
    const float* __restrict__ goal, const float* __restrict__ action,
    const float* __restrict__ Wd, const float* __restrict__ w,
    const float* __restrict__ a, float* __restrict__ ws)
{
    const int b = blockIdx.x;
    const int t = threadIdx.x;
    const int wid  = t >> 6;
    const int lane = t & 63;
    float* Q  = ws + WS_Q;
    float* WA = ws + WS_WA;
    float* WB = ws + WS_WB;

    if (b < 16) {
        const int z  = b >> 2;
        const int rg = b & 3;
        const int hbase = rg*64 + wid*16;
        const f32x4 aB = *(const f32x4*)(a + lane*4);
        const f32x4 aA = *(const f32x4*)(a + HH + lane*4);
#pragma unroll 4
        for (int rr = 0; rr < 16; ++rr) {
            const int h = hbase + rr;
            const f32x4 w4 = *(const f32x4*)(w + z*HH*HH + h*HH + lane*4);
            float dA = w4.x*aA.x + w4.y*aA.y + w4.z*aA.z + w4.w*aA.w;
            float dB = w4.x*aB.x + w4.y*aB.y + w4.z*aB.z + w4.w*aB.w;
#pragma unroll
            for (int off = 32; off; off >>= 1) {
                dA += __shfl_xor(dA, off);
                dB += __shfl_xor(dB, off);
            }
            if (lane == 0) { WA[z*HH + h] = dA; WB[z*HH + h] = dB; }
        }
    } else {
        const int i = (b - 16)*4 + wid;
        const int d = lane;
        float a0 = action[2*i], a1 = action[2*i+1];
        float g0 = goal[2*i],   g1 = goal[2*i+1];
        Q[i*64 + d] = a0*Wd[4*64+d] + a1*Wd[5*64+d]
                    + g0*Wd[6*64+d] + g1*Wd[7*64+d];
    }
}

// grid 512: block = (n, half hh); j in [hh*128,+128), 8 one-barrier chunks of 16.
// P-row inline, B-frags direct from Wg, tanh inline (no T table).
__global__ __launch_bounds__(256, 2) void gat_partial_kernel(
    const float* __restrict__ ahs, const float* __restrict__ ghs,
    const float* __restrict__ goal, const float* __restrict__ action,
    const float* __restrict__ Wd, const float* __restrict__ b_dist,
    const float* __restrict__ Wg, const float* __restrict__ b_gate,
    float* __restrict__ ws)
{
    const int n    = blockIdx.x >> 1;
    const int hh   = blockIdx.x & 1;
    const int t    = threadIdx.x;
    const int wid  = t >> 6;
    const int lane = t & 63;
    const int quad = lane >> 4;
    const int l15  = lane & 15;
    const int zg   = quad;
    const int jj   = l15;
    const int n0   = wid * 64;

    const float* Q  = ws + WS_Q;
    const float* WA = ws + WS_WA;
    const float* WB = ws + WS_WB;
    float* PV = ws + WS_PV;
    float* ML = ws + WS_ML;

    __shared__ __align__(16) float part[2][4][16][4];
    __shared__ __align__(16) float alpha_w[4][16][4];
    __shared__ __align__(16) float vred[16][260];

    int hcol[4];
#pragma unroll
    for (int nt = 0; nt < 4; ++nt) hcol[nt] = n0 + nt*16 + l15;

    // B-fragments direct from Wg (f32 -> bf16); coalesced across l15
    short8 bfrag[4][2];
#pragma unroll
    for (int nt = 0; nt < 4; ++nt)
#pragma unroll
        for (int kh = 0; kh < 2; ++kh) {
            ushort hv[8];
#pragma unroll
            for (int i = 0; i < 8; ++i) {
                const int d = kh*32 + quad*8 + i;
                hv[i] = f2bf(Wg[d*HH + hcol[nt]]);
            }
            bfrag[nt][kh] = *(short8*)hv;
        }

    float wa_reg[4][4];
    float bgv[4], gval[4];
#pragma unroll
    for (int nt = 0; nt < 4; ++nt) {
#pragma unroll
        for (int z = 0; z < 4; ++z) wa_reg[z][nt] = WA[z*HH + hcol[nt]];
        bgv[nt]  = b_gate[hcol[nt]];
        gval[nt] = ghs[n*HH + hcol[nt]];
    }

    // P-row inline: pnA[kh][i], k = kh*32 + quad*8 + i
    float pnA[2][8];
    {
        const float a0 = action[2*n], a1 = action[2*n+1];
        const float g0 = goal[2*n],   g1 = goal[2*n+1];
#pragma unroll
        for (int kh = 0; kh < 2; ++kh)
#pragma unroll
            for (int i = 0; i < 8; ++i) {
                const int k = kh*32 + quad*8 + i;
                pnA[kh][i] = a0*Wd[0*64+k] + a1*Wd[1*64+k]
                           + g0*Wd[2*64+k] + g1*Wd[3*64+k] + b_dist[k];
            }
    }

    float vacc[4][4];
    {
        float av[4];
#pragma unroll
        for (int nt = 0; nt < 4; ++nt) av[nt] = ahs[n*HH + hcol[nt]];
#pragma unroll
        for (int z = 0; z < 4; ++z)
#pragma unroll
            for (int nt = 0; nt < 4; ++nt)
                vacc[z][nt] = (hh == 0 && quad == 0) ? av[nt] : 0.f;
    }

    // redundant per-wave softmax init: lane (zg,jj) sums h=jj*16..+16
    float cz_r, m_r, l_r;
    {
        float pc = 0.f, ps = 0.f;
        const int hb = jj*16;
#pragma unroll
        for (int i4 = 0; i4 < 4; ++i4) {
            f32x4 av = *(const f32x4*)(ahs + n*HH + hb + i4*4);
            f32x4 wb = *(const f32x4*)(WB + zg*HH + hb + i4*4);
            f32x4 wa = *(const f32x4*)(WA + zg*HH + hb + i4*4);
            pc = fmaf(av.x, wb.x, pc); pc = fmaf(av.y, wb.y, pc);
            pc = fmaf(av.z, wb.z, pc); pc = fmaf(av.w, wb.w, pc);
            ps = fmaf(av.x, wa.x, ps); ps = fmaf(av.y, wa.y, ps);
            ps = fmaf(av.z, wa.z, ps); ps = fmaf(av.w, wa.w, ps);
        }
        pc = red16(pc); ps = red16(ps);
        cz_r = pc;
        if (hh == 0) {
            float sc = pc + ps;
            m_r = sc > 0.f ? sc : 0.2f * sc;
            l_r = 1.0f;
        } else {
            m_r = -__builtin_inff();
            l_r = 0.0f;
        }
    }

    for (int cc = 0; cc < 8; ++cc) {
        const int j0  = hh*128 + cc*16;
        const int par = cc & 1;

        // prefetch ahs values for tanh (independent loads)
        float hval[4][4];
#pragma unroll
        for (int r = 0; r < 4; ++r) {
            const int jg = j0 + quad*4 + r;
#pragma unroll
            for (int nt = 0; nt < 4; ++nt)
                hval[nt][r] = ahs[jg*HH + hcol[nt]];
        }

        // A-frags from Q + P
        short8 afrag[2];
#pragma unroll
        for (int kh = 0; kh < 2; ++kh) {
            const float* qrow = Q + (j0 + l15)*64 + kh*32 + quad*8;
            f32x4 qa = *(const f32x4*)qrow;
            f32x4 qb = *(const f32x4*)(qrow + 4);
            ushort hv[8];
            hv[0] = f2bf(fmaxf(pnA[kh][0] + qa.x, 0.f));
            hv[1] = f2bf(fmaxf(pnA[kh][1] + qa.y, 0.f));
            hv[2] = f2bf(fmaxf(pnA[kh][2] + qa.z, 0.f));
            hv[3] = f2bf(fmaxf(pnA[kh][3] + qa.w, 0.f));
            hv[4] = f2bf(fmaxf(pnA[kh][4] + qb.x, 0.f));
            hv[5] = f2bf(fmaxf(pnA[kh][5] + qb.y, 0.f));
            hv[6] = f2bf(fmaxf(pnA[kh][6] + qb.z, 0.f));
            hv[7] = f2bf(fmaxf(pnA[kh][7] + qb.w, 0.f));
            afrag[kh] = *(short8*)hv;
        }

        f32x4 acc[4];
#pragma unroll
        for (int nt = 0; nt < 4; ++nt) {
            f32x4 a4 = (f32x4){0.f,0.f,0.f,0.f};
            a4 = __builtin_amdgcn_mfma_f32_16x16x32_bf16(afrag[0], bfrag[nt][0], a4, 0, 0, 0);
            a4 = __builtin_amdgcn_mfma_f32_16x16x32_bf16(afrag[1], bfrag[nt][1], a4, 0, 0, 0);
            acc[nt] = a4;
        }

        // gate epilogue: tanh inline
        float vals[4][4];
#pragma unroll
        for (int r = 0; r < 4; ++r) {
            const int jg = j0 + quad*4 + r;
            const bool diag = (jg == n);
#pragma unroll
            for (int nt = 0; nt < 4; ++nt) {
                float u = acc[nt][r] + bgv[nt];
                float g = 1.0f / (1.0f + __expf(-u));
                vals[nt][r] = diag ? gval[nt] : g * tanhf(hval[nt][r]);
            }
        }

        // score partials
#pragma unroll
        for (int z = 0; z < 4; ++z) {
            float pp[4];
#pragma unroll
            for (int r = 0; r < 4; ++r) {
                float s = 0.f;
#pragma unroll
                for (int nt = 0; nt < 4; ++nt)
                    s = fmaf(vals[nt][r], wa_reg[z][nt], s);
                pp[r] = red16(s);
            }
            if (l15 == z) {
#pragma unroll
                for (int r = 0; r < 4; ++r)
                    part[par][z][quad*4 + r][wid] = pp[r];
            }
        }
        __syncthreads();   // only barrier per chunk

        // redundant lane-parallel softmax
        float scl0, scl1, scl2, scl3;
        {
            f32x4 pr = *(const f32x4*)&part[par][zg][jj][0];
            float s = cz_r + ((pr.x + pr.y) + (pr.z + pr.w));
            float e = s > 0.f ? s : 0.2f * s;
            float mx = red16max(e);
            float m_new = fmaxf(m_r, mx);
            float at = __expf(e - m_new);
            float ss = red16(at);
            float scale = __expf(m_r - m_new);
            l_r = l_r * scale + ss;
            m_r = m_new;
            alpha_w[wid][jj][zg] = at;
            scl0 = __shfl(scale, 0);
            scl1 = __shfl(scale, 16);
            scl2 = __shfl(scale, 32);
            scl3 = __shfl(scale, 48);
        }
#pragma unroll
        for (int nt = 0; nt < 4; ++nt) {
            vacc[0][nt] *= scl0; vacc[1][nt] *= scl1;
            vacc[2][nt] *= scl2; vacc[3][nt] *= scl3;
        }
#pragma unroll
        for (int r = 0; r < 4; ++r) {
            f32x4 al = *(const f32x4*)&alpha_w[wid][quad*4 + r][0];
#pragma unroll
            for (int nt = 0; nt < 4; ++nt) {
                float v = vals[nt][r];
                vacc[0][nt] = fmaf(al.x, v, vacc[0][nt]);
                vacc[1][nt] = fmaf(al.y, v, vacc[1][nt]);
                vacc[2][nt] = fmaf(al.z, v, vacc[2][nt]);
                vacc[3][nt] = fmaf(al.w, v, vacc[3][nt]);
            }
        }
    }

    // cross-quad reduce, write PV + ML
#pragma unroll
    for (int z = 0; z < 4; ++z)
#pragma unroll
        for (int nt = 0; nt < 4; ++nt)
            vred[quad*4 + z][hcol[nt]] = vacc[z][nt];
    __syncthreads();
#pragma unroll
    for (int z = 0; z < 4; ++z) {
        float s = (vred[0*4+z][t] + vred[1*4+z][t]) + (vred[2*4+z][t] + vred[3*4+z][t]);
        PV[((size_t)(hh*4 + z)*NN + n)*HH + t] = s;
    }
    if (wid == 0 && l15 == 0) {
        ML[((hh*4 + zg)*NN + n)*2 + 0] = m_r;
        ML[((hh*4 + zg)*NN + n)*2 + 1] = l_r;
    }
}

// grid 128: (16 n-tiles) x (8 f-tiles of 32). Fused merge + split-bf16 MFMA, w read direct.
__global__ __launch_bounds__(256) void gat_out_kernel(
    const float* __restrict__ w, const float* __restrict__ bias,
    const float* __restrict__ ws, float* __restrict__ out)
{
    const int n0 = (blockIdx.x >> 3) * 16;
    const int f0 = (blockIdx.x & 7) * 32;
    const int t    = threadIdx.x;
    const int wid  = t >> 6;
    const int lane = t & 63;
    const int quad = lane >> 4;
    const int l15  = lane & 15;

    const float* PV = ws + WS_PV;
    const float* ML = ws + WS_ML;

    __shared__ __align__(16) float redc[3*2*16*16];   // [wid-1][nt][row][l15]
    __shared__ __align__(16) float sq[16][4][2];

    if (t < 128) {
        const int n_i = t >> 3, z = (t >> 1) & 3, q = t & 1;
        float m = ML[((q*4 + z)*NN + n0 + n_i)*2 + 0];
        float l = ML[((q*4 + z)*NN + n0 + n_i)*2 + 1];
        float mm = fmaxf(m, __shfl_xor(m, 1));
        float s  = __expf(m - mm);
        float ls = l * s;
        ls += __shfl_xor(ls, 1);
        sq[n_i][z][q] = s / ls;
    }
    __syncthreads();

    // wave wid owns z=wid (k stripe [wid*256,+256)); A-frags in registers
    f32x4 acc[2];
    acc[0] = (f32x4){0.f,0.f,0.f,0.f};
    acc[1] = (f32x4){0.f,0.f,0.f,0.f};

    const float s0 = sq[l15][wid][0];
    const float s1 = sq[l15][wid][1];
    const float* pv0 = PV + ((size_t)(0*4 + wid)*NN + n0 + l15)*HH;
    const float* pv1 = PV + ((size_t)(1*4 + wid)*NN + n0 + l15)*HH;

    for (int ks = 0; ks < 8; ++ks) {
        const int kp = ks*32 + quad*8;
        f32x4 p0a = *(const f32x4*)(pv0 + kp);
        f32x4 p0b = *(const f32x4*)(pv0 + kp + 4);
        f32x4 p1a = *(const f32x4*)(pv1 + kp);
        f32x4 p1b = *(const f32x4*)(pv1 + kp + 4);
        float v[8];
        v[0] = s0*p0a.x + s1*p1a.x; v[1] = s0*p0a.y + s1*p1a.y;
        v[2] = s0*p0a.z + s1*p1a.z; v[3] = s0*p0a.w + s1*p1a.w;
        v[4] = s0*p0b.x + s1*p1b.x; v[5] = s0*p0b.y + s1*p1b.y;
        v[6] = s0*p0b.z + s1*p1b.z; v[7] = s0*p0b.w + s1*p1b.w;
        ushort hi[8], lo[8];
#pragma unroll
        for (int c = 0; c < 8; ++c) {
            hi[c] = f2bf(v[c]);
            lo[c] = f2bf(v[c] - bf2f(hi[c]));
        }
        short8 ah = *(short8*)hi;
        short8 al = *(short8*)lo;
        const int kg = wid*256 + kp;        // global k for this fragment
#pragma unroll
        for (int nt = 0; nt < 2; ++nt) {
            const int f = f0 + nt*16 + l15;
            ushort bhv[8], blv[8];
#pragma unroll
            for (int i = 0; i < 8; ++i) {
                float wv = w[(size_t)(kg + i)*HH + f];
                bhv[i] = f2bf(wv);
                blv[i] = f2bf(wv - bf2f(bhv[i]));
            }
            short8 bh = *(short8*)bhv;
            short8 bl = *(short8*)blv;
            acc[nt] = __builtin_amdgcn_mfma_f32_16x16x32_bf16(ah, bh, acc[nt], 0, 0, 0);
            acc[nt] = __builtin_amdgcn_mfma_f32_16x16x32_bf16(ah, bl, acc[nt], 0, 0, 0);
            acc[nt] = __builtin_amdgcn_mfma_f32_16x16x32_bf16(al, bh, acc[nt], 0, 0, 0);
        }
    }
    __syncthreads();

    if (wid > 0) {
#pragma unroll
        for (int nt = 0; nt < 2; ++nt)
#pragma unroll
            for (int r = 0; r < 4; ++r)
                redc[(((wid-1)*2 + nt)*16 + quad*4 + r)*16 + l15] = acc[nt][r];
    }
    __syncthreads();
    if (wid == 0) {
#pragma unroll
        for (int nt = 0; nt < 2; ++nt) {
            const int f = f0 + nt*16 + l15;
            float bv = bias[f];
#pragma unroll
            for (int r = 0; r < 4; ++r) {
                const int row = quad*4 + r;
                float s = acc[nt][r]
                        + redc[((0*2 + nt)*16 + row)*16 + l15]
                        + redc[((1*2 + nt)*16 + row)*16 + l15]
                        + redc[((2*2 + nt)*16 + row)*16 + l15];
                out[(size_t)(n0 + row)*HH + f] = fmaxf(0.25f * s, 0.f) + bv;
            }
        }
    }
}

extern "C" void kernel_launch(void* const* d_in, const int* in_sizes, int n_in,
                              void* d_out, int out_size, void* d_ws, size_t ws_size,
                              hipStream_t stream)
{
    const float* ahs    = (const float*)d_in[0];
    const float* ghs    = (const float*)d_in[1];
    const float* goal   = (const float*)d_in[2];
    const float* action = (const float*)d_in[3];
    const float* Wd     = (const float*)d_in[4];
    const float* b_dist = (const float*)d_in[5];
    const float* Wg     = (const float*)d_in[6];
    const float* b_gate = (const float*)d_in[7];
    const float* w      = (const float*)d_in[8];
    const float* a      = (const float*)d_in[9];
    const float* bias   = (const float*)d_in[10];
    float* ws   = (float*)d_ws;     // needs 2,187,264 bytes
    float* outp = (float*)d_out;

    precompute_kernel<<<80, 256, 0, stream>>>(goal, action, Wd, w, a, ws);
    gat_partial_kernel<<<512, 256, 0, stream>>>(ahs, ghs, goal, action, Wd, b_dist,
                                                Wg, b_gate, ws);
    gat_out_kernel<<<128, 256, 0, stream>>>(w, bias, ws, outp);
}